// Round 8
// baseline (987.840 us; speedup 1.0000x reference)
//
#include <hip/hip_runtime.h>
#include <math.h>

using f32x4    = __attribute__((ext_vector_type(4))) float;
using short8   = __attribute__((ext_vector_type(8))) short;
using ushort8  = __attribute__((ext_vector_type(8))) unsigned short;
using ushort4v = __attribute__((ext_vector_type(4))) unsigned short;
using u32x4    = __attribute__((ext_vector_type(4))) unsigned int;

#define D_DIM 768
#define H_DIM 3072

// 3-level radix select on |w| bit pattern: 14 + 9 + 9 bits.
#define L1_BITS 14
#define L1_SIZE 16384

// ---------------- ws layout (bytes) ----------------
static const size_t HIST1_OFF = 0;                        // 131072
static const size_t HIST2_OFF = 131072;                   // 8192
static const size_t HIST3_OFF = 139264;                   // 8192
static const size_t SUM_OFF   = 147456;                   // double[2]
static const size_t THR_OFF   = 147472;                   // double[2]
static const size_t META_OFF  = 147488;                   // u32[32] -> 147616
static const size_t MU2A_OFF  = 147616;                   // f32[32768] row-sum acc
static const size_t SS2A_OFF  = 278688;                   // f32[32768] row-sq acc
static const size_t ZERO_BYTES= 409760;
static const size_t S1_OFF    = 409760;                   // f32[768]
static const size_t S2_OFF    = 412832;                   // f32[768]
static const size_t MU2_OFF   = 415904;                   // f32[32768]
static const size_t RS2_OFF   = 546976;                   // f32[32768]
static const size_t WQ1_OFF   = 5242880;                  // bf16[3072*768]
static const size_t WQ2_OFF   = 9961472;                  // bf16[768*3072]
static const size_t H1_OFF    = 16777216;                 // bf16[32768*3072]
// xn (bf16 LN1(x), 48 MB) lives in d_out until gemm2 overwrites it (stream-ordered).

__device__ __forceinline__ unsigned short f2bf(float f) {
    unsigned u = __float_as_uint(f);
    u += 0x7fffu + ((u >> 16) & 1u);
    return (unsigned short)(u >> 16);
}
__device__ __forceinline__ float bf2f(unsigned short s) {
    return __uint_as_float(((unsigned)s) << 16);
}

__device__ __forceinline__ void gload16(const unsigned short* g, unsigned short* l) {
    __builtin_amdgcn_global_load_lds(
        (const __attribute__((address_space(1))) unsigned int*)g,
        (__attribute__((address_space(3))) unsigned int*)l, 16, 0, 0);
}

// ---------------- L1: LDS-privatized 14-bit histogram of |w| + fp64 abs-sum ----------------
__global__ void hist_abs_kernel(const float* __restrict__ W1, int n1,
                                const float* __restrict__ W2, int n2,
                                unsigned* __restrict__ hist, double* __restrict__ sums) {
    __shared__ unsigned lh[L1_SIZE];
    const int t = blockIdx.y;
    const float* W = t ? W2 : W1;
    const int n = t ? n2 : n1;
    unsigned* hg = hist + (size_t)t * L1_SIZE;

    for (int i = threadIdx.x; i < L1_SIZE; i += 256) lh[i] = 0;
    __syncthreads();

    int tid = blockIdx.x * blockDim.x + threadIdx.x;
    int stride = gridDim.x * blockDim.x;
    double local = 0.0;
    int n4 = n >> 2;
    for (int i = tid; i < n4; i += stride) {
        f32x4 w = ((const f32x4*)W)[i];
#pragma unroll
        for (int j = 0; j < 4; j++) {
            float a = fabsf(w[j]);
            local += (double)a;
            atomicAdd(&lh[__float_as_uint(a) >> (32 - L1_BITS)], 1u);
        }
    }
    for (int i = (n4 << 2) + tid; i < n; i += stride) {
        float a = fabsf(W[i]);
        local += (double)a;
        atomicAdd(&lh[__float_as_uint(a) >> (32 - L1_BITS)], 1u);
    }
    __syncthreads();
    for (int i = threadIdx.x; i < L1_SIZE; i += 256) {
        unsigned c = lh[i];
        if (c) atomicAdd(&hg[i], c);
    }
#pragma unroll
    for (int off = 32; off >= 1; off >>= 1) local += __shfl_down(local, off);
    if ((threadIdx.x & 63) == 0) atomicAdd(&sums[t], local);
}

// ---------------- L1 scan ----------------
__global__ void scan1_kernel(const unsigned* __restrict__ hist, unsigned* __restrict__ meta_u,
                             const float* __restrict__ sparsity, int n1, int n2) {
    __shared__ unsigned partial[256];
    __shared__ unsigned basearr[256];
    for (int t = 0; t < 2; t++) {
        const unsigned* h = hist + (size_t)t * L1_SIZE;
        int n = t ? n2 : n1;
        double p = (double)(*sparsity) * (double)(n - 1);
        unsigned kA = (unsigned)floor(p);
        unsigned kB = kA + 1; if (kB > (unsigned)(n - 1)) kB = (unsigned)(n - 1);
        int b0 = threadIdx.x * 64;
        unsigned s_local = 0;
#pragma unroll
        for (int b = 0; b < 64; b += 4) {
            u32x4 v = *(const u32x4*)&h[b0 + b];
            s_local += v[0] + v[1] + v[2] + v[3];
        }
        partial[threadIdx.x] = s_local;
        __syncthreads();
        if (threadIdx.x == 0) {
            unsigned run = 0;
            for (int i = 0; i < 256; i++) { unsigned tmp = partial[i]; basearr[i] = run; run += tmp; }
        }
        __syncthreads();
        unsigned cumbase = basearr[threadIdx.x];
        for (int s = 0; s < 2; s++) {
            unsigned rank = s ? kB : kA;
            if (rank >= cumbase && rank < cumbase + s_local) {
                unsigned cum = cumbase;
                for (int b = 0; b < 64; b++) {
                    unsigned c = h[b0 + b];
                    if (rank < cum + c) { meta_u[s * 4 + t] = (unsigned)(b0 + b); meta_u[s * 4 + 2 + t] = rank - cum; break; }
                    cum += c;
                }
            }
        }
        __syncthreads();
    }
}

// ---------------- L2/L3 histograms (512 buckets, LDS-privatized) ----------
template<int LVL>
__global__ void histN_kernel(const float* __restrict__ W1, int n1,
                             const float* __restrict__ W2, int n2,
                             const unsigned* __restrict__ meta_u, unsigned* __restrict__ histo) {
    __shared__ unsigned hA[512], hB[512];
    const int t = blockIdx.y;
    const float* W = t ? W2 : W1;
    const int n = t ? n2 : n1;
    for (int i = threadIdx.x; i < 512; i += 256) { hA[i] = 0; hB[i] = 0; }
    __syncthreads();
    const int inbase = (LVL == 2) ? 0 : 16;
    unsigned pa = meta_u[inbase + 0 + t], pb = meta_u[inbase + 4 + t];
    int tid = blockIdx.x * blockDim.x + threadIdx.x;
    int stride = gridDim.x * blockDim.x;
    int n4 = n >> 2;
    for (int i = tid; i < n4; i += stride) {
        f32x4 w = ((const f32x4*)W)[i];
#pragma unroll
        for (int j = 0; j < 4; j++) {
            unsigned u = __float_as_uint(fabsf(w[j]));
            unsigned pf  = (LVL == 2) ? (u >> 18) : (u >> 9);
            unsigned idx = (LVL == 2) ? ((u >> 9) & 0x1FFu) : (u & 0x1FFu);
            if (pf == pa) atomicAdd(&hA[idx], 1u);
            if (pf == pb) atomicAdd(&hB[idx], 1u);
        }
    }
    for (int i = (n4 << 2) + tid; i < n; i += stride) {
        unsigned u = __float_as_uint(fabsf(W[i]));
        unsigned pf  = (LVL == 2) ? (u >> 18) : (u >> 9);
        unsigned idx = (LVL == 2) ? ((u >> 9) & 0x1FFu) : (u & 0x1FFu);
        if (pf == pa) atomicAdd(&hA[idx], 1u);
        if (pf == pb) atomicAdd(&hB[idx], 1u);
    }
    __syncthreads();
    for (int i = threadIdx.x; i < 512; i += 256) {
        unsigned a = hA[i]; if (a) atomicAdd(&histo[(size_t)(t * 2 + 0) * 512 + i], a);
        unsigned b = hB[i]; if (b) atomicAdd(&histo[(size_t)(t * 2 + 1) * 512 + i], b);
    }
}

// ---------------- L2 scan ------------
__global__ void scan_mid_kernel(const unsigned* __restrict__ histo, unsigned* __restrict__ meta_u) {
    int wave = threadIdx.x >> 6, lane = threadIdx.x & 63;
    int s = wave >> 1, t = wave & 1;
    const unsigned* h = histo + (size_t)(t * 2 + s) * 512;
    unsigned rank = meta_u[s * 4 + 2 + t];
    unsigned pfx  = meta_u[s * 4 + t];
    u32x4 ca = *(const u32x4*)&h[lane * 8];
    u32x4 cb = *(const u32x4*)&h[lane * 8 + 4];
    unsigned cc[8] = {ca[0], ca[1], ca[2], ca[3], cb[0], cb[1], cb[2], cb[3]};
    unsigned csum = cc[0] + cc[1] + cc[2] + cc[3] + cc[4] + cc[5] + cc[6] + cc[7];
    unsigned inc = csum;
#pragma unroll
    for (int off = 1; off < 64; off <<= 1) {
        unsigned v = __shfl_up(inc, off, 64);
        if (lane >= off) inc += v;
    }
    unsigned pre = inc - csum;
    if (rank >= pre && rank < pre + csum) {
        unsigned cum = pre, rem = 0, bucket = 0; bool found = false;
#pragma unroll
        for (int j = 0; j < 8; j++) {
            if (!found) {
                if (rank < cum + cc[j]) { bucket = lane * 8 + j; rem = rank - cum; found = true; }
                else cum += cc[j];
            }
        }
        meta_u[16 + s * 4 + t] = (pfx << 9) | bucket;
        meta_u[16 + s * 4 + 2 + t] = rem;
    }
}

// ---------------- L3 scan -> fp64 threshold + scale ----------------------
__global__ void scan_fin_kernel(const unsigned* __restrict__ histo, unsigned* __restrict__ meta_u,
                                const double* __restrict__ sums, const float* __restrict__ sparsity,
                                double* __restrict__ thr, int n1, int n2) {
    __shared__ unsigned vbs[4];
    int wave = threadIdx.x >> 6, lane = threadIdx.x & 63;
    int s = wave >> 1, t = wave & 1;
    const unsigned* h = histo + (size_t)(t * 2 + s) * 512;
    unsigned rank = meta_u[16 + s * 4 + 2 + t];
    unsigned pfx  = meta_u[16 + s * 4 + t];
    u32x4 ca = *(const u32x4*)&h[lane * 8];
    u32x4 cb = *(const u32x4*)&h[lane * 8 + 4];
    unsigned cc[8] = {ca[0], ca[1], ca[2], ca[3], cb[0], cb[1], cb[2], cb[3]};
    unsigned csum = cc[0] + cc[1] + cc[2] + cc[3] + cc[4] + cc[5] + cc[6] + cc[7];
    unsigned inc = csum;
#pragma unroll
    for (int off = 1; off < 64; off <<= 1) {
        unsigned v = __shfl_up(inc, off, 64);
        if (lane >= off) inc += v;
    }
    unsigned pre = inc - csum;
    if (rank >= pre && rank < pre + csum) {
        unsigned cum = pre, bucket = 0; bool found = false;
#pragma unroll
        for (int j = 0; j < 8; j++) {
            if (!found) {
                if (rank < cum + cc[j]) { bucket = lane * 8 + j; found = true; }
                else cum += cc[j];
            }
        }
        vbs[t * 2 + s] = (pfx << 9) | bucket;
    }
    __syncthreads();
    if (threadIdx.x < 2) {
        int tt = threadIdx.x;
        int n = tt ? n2 : n1;
        double a = (double)__uint_as_float(vbs[tt * 2 + 0]);
        double b = (double)__uint_as_float(vbs[tt * 2 + 1]);
        double p = (double)(*sparsity) * (double)(n - 1);
        double tfr = p - floor(p);
        double th = (tfr >= 0.5) ? (b - (b - a) * (1.0 - tfr)) : (a + (b - a) * tfr);
        thr[tt] = th;
        ((float*)meta_u)[24 + tt] = (float)(sums[tt] / (double)n);
    }
}

// ---------------- ternary quantize: wq1 = sign, wq2 = sign*bf16(g2[k]) ----------------
__global__ void quantize_kernel(const float* __restrict__ W1, int n1,
                                const float* __restrict__ W2, int n2,
                                const double* __restrict__ thr, const float* __restrict__ g2,
                                unsigned short* __restrict__ wq1, unsigned short* __restrict__ wq2) {
    int tid = blockIdx.x * blockDim.x + threadIdx.x;
    int stride = gridDim.x * blockDim.x;
    for (int t = 0; t < 2; t++) {
        const float* W = t ? W2 : W1;
        unsigned short* O = t ? wq2 : wq1;
        int n = t ? n2 : n1;
        double th = thr[t];
        int n4 = n >> 2;
        for (int i = tid; i < n4; i += stride) {
            f32x4 w = ((const f32x4*)W)[i];
            ushort4v q;
            if (t == 0) {
#pragma unroll
                for (int j = 0; j < 4; j++) {
                    unsigned short v = 0;
                    if ((double)fabsf(w[j]) > th) v = (w[j] > 0.f) ? 0x3F80u : 0xBF80u;
                    q[j] = v;
                }
            } else {
                int k4 = (i % (H_DIM / 4)) * 4;
                f32x4 g = *(const f32x4*)&g2[k4];
#pragma unroll
                for (int j = 0; j < 4; j++) {
                    unsigned short v = 0;
                    if ((double)fabsf(w[j]) > th) {
                        unsigned short gb = f2bf(g[j]);
                        v = (w[j] > 0.f) ? gb : (unsigned short)(gb ^ 0x8000u);
                    }
                    q[j] = v;
                }
            }
            ((ushort4v*)O)[i] = q;
        }
    }
}

// ---------------- column correction sums for gemm2: S1[c]=Σ bf16(g)·q, S2[c]=Σ bβ·q ----------
__global__ void colsum_kernel(const float* __restrict__ W2, const double* __restrict__ thr,
                              const float* __restrict__ g2, const float* __restrict__ bln2,
                              float* __restrict__ S1, float* __restrict__ S2) {
    int wave = threadIdx.x >> 6, lane = threadIdx.x & 63;
    int c = blockIdx.x * 4 + wave;
    const float* wr = W2 + (size_t)c * H_DIM;
    double th = thr[1];
    float s1 = 0.f, s2 = 0.f;
    for (int k = lane * 4; k < H_DIM; k += 256) {
        f32x4 w = *(const f32x4*)&wr[k];
        f32x4 g = *(const f32x4*)&g2[k];
        f32x4 b = *(const f32x4*)&bln2[k];
#pragma unroll
        for (int j = 0; j < 4; j++) {
            if ((double)fabsf(w[j]) > th) {
                float sg = (w[j] > 0.f) ? 1.f : -1.f;
                s1 += sg * bf2f(f2bf(g[j]));
                s2 += sg * b[j];
            }
        }
    }
#pragma unroll
    for (int off = 32; off >= 1; off >>= 1) { s1 += __shfl_xor(s1, off); s2 += __shfl_xor(s2, off); }
    if (lane == 0) { S1[c] = s1; S2[c] = s2; }
}

// ---------------- LN1: stats + apply, write xn bf16 ----------------
__global__ void ln1_apply_kernel(const float* __restrict__ x, const float* __restrict__ g,
                                 const float* __restrict__ b, unsigned short* __restrict__ xn, int M) {
    int wave = threadIdx.x >> 6, lane = threadIdx.x & 63;
    int row = blockIdx.x * 4 + wave;
    if (row >= M) return;
    const float* xr = x + (size_t)row * D_DIM;
    f32x4 xv[3];
    float s = 0.f, s2 = 0.f;
#pragma unroll
    for (int i = 0; i < 3; i++) {
        xv[i] = *(const f32x4*)&xr[lane * 4 + i * 256];
#pragma unroll
        for (int j = 0; j < 4; j++) { s += xv[i][j]; s2 += xv[i][j] * xv[i][j]; }
    }
#pragma unroll
    for (int off = 32; off >= 1; off >>= 1) { s += __shfl_xor(s, off); s2 += __shfl_xor(s2, off); }
    float m = s / (float)D_DIM;
    float var = s2 / (float)D_DIM - m * m;
    float rs = 1.f / sqrtf(var + 1e-5f);
    unsigned short* xo = xn + (size_t)row * D_DIM;
#pragma unroll
    for (int i = 0; i < 3; i++) {
        int k = lane * 4 + i * 256;
        f32x4 gg = *(const f32x4*)&g[k];
        f32x4 bb = *(const f32x4*)&b[k];
        ushort4v o;
#pragma unroll
        for (int j = 0; j < 4; j++) o[j] = f2bf((xv[i][j] - m) * rs * gg[j] + bb[j]);
        *(ushort4v*)&xo[k] = o;
    }
}

// ---------------- finalize LN2 stats from accumulated row sums ----------------
__global__ void ln2stats_kernel(const float* __restrict__ sa, const float* __restrict__ sb,
                                float* __restrict__ mu, float* __restrict__ rs, int M) {
    int i = blockIdx.x * 256 + threadIdx.x;
    if (i >= M) return;
    float m = sa[i] / (float)H_DIM;
    float var = sb[i] / (float)H_DIM - m * m;
    mu[i] = m;
    rs[i] = 1.f / sqrtf(var + 1e-5f);
}

// ---------------- bf16 GEMM: C = A @ Bq^T, 128x128 tile, BK=64, gload_lds + XOR swizzle ----
// 1D grid with XCD-chunked m-rows: blocks sharing an A-panel land on one XCD's L2.
// EPI 1 (gemm1): h1 = bf16(gelu(acc*scale+bias)); accumulate row Σ/Σ² (bf16-rounded) via atomics.
// EPI 2 (gemm2): out = scale*(rs[r]*(acc - mu[r]*S1[c]) + S2[c]) + bias[c], fp32.
template<int KD, int NBN, int EPI>
__launch_bounds__(256)
__global__ void gemm_tern_kernel(const unsigned short* __restrict__ A,
                                 const unsigned short* __restrict__ Bq,
                                 const float* __restrict__ bias,
                                 const float* __restrict__ meta_f, int sidx,
                                 void* __restrict__ outp,
                                 float* __restrict__ rsum_g, float* __restrict__ rsum2_g,
                                 const float* __restrict__ mu2, const float* __restrict__ rs2,
                                 const float* __restrict__ S1, const float* __restrict__ S2) {
    __shared__ unsigned short As[128 * 64];
    __shared__ unsigned short Bs[128 * 64];
    const int bid = blockIdx.x;
    const int xcd = bid & 7, idx = bid >> 3;
    const int mb = (idx / NBN) * 8 + xcd;
    const int nb = idx % NBN;
    const int m0 = mb * 128, n0 = nb * 128;
    const float scale = meta_f[sidx];
    const int tt = threadIdx.x, lane = tt & 63, wave = tt >> 6;
    const int wm = (wave & 1) * 64, wn = (wave >> 1) * 64;
    const int l16 = lane & 15, l4 = lane >> 4;
    const int srow = tt >> 3, schunk = tt & 7;

    f32x4 acc[4][4];
#pragma unroll
    for (int mi = 0; mi < 4; mi++)
#pragma unroll
        for (int ni = 0; ni < 4; ni++) acc[mi][ni] = (f32x4){0.f, 0.f, 0.f, 0.f};

    for (int k0 = 0; k0 < KD; k0 += 64) {
#pragma unroll
        for (int r = 0; r < 4; r++) {
            int row = r * 32 + srow;
            int sc = (schunk ^ (row & 7)) << 3;
            gload16(&A[(size_t)(m0 + row) * KD + k0 + sc], &As[(size_t)tt * 8 + r * 2048]);
        }
#pragma unroll
        for (int r = 0; r < 4; r++) {
            int row = r * 32 + srow;
            int sc = (schunk ^ (row & 7)) << 3;
            gload16(&Bq[(size_t)(n0 + row) * KD + k0 + sc], &Bs[(size_t)tt * 8 + r * 2048]);
        }
        __syncthreads();
#pragma unroll
        for (int ks = 0; ks < 2; ks++) {
            short8 af[4], bf_[4];
#pragma unroll
            for (int i = 0; i < 4; i++) {
                int ar = wm + i * 16 + l16;
                af[i] = *(const short8*)&As[ar * 64 + (((ks * 4 + l4) ^ (ar & 7)) << 3)];
                int br = wn + i * 16 + l16;
                bf_[i] = *(const short8*)&Bs[br * 64 + (((ks * 4 + l4) ^ (br & 7)) << 3)];
            }
#pragma unroll
            for (int mi = 0; mi < 4; mi++)
#pragma unroll
                for (int ni = 0; ni < 4; ni++)
                    acc[mi][ni] = __builtin_amdgcn_mfma_f32_16x16x32_bf16(af[mi], bf_[ni], acc[mi][ni], 0, 0, 0);
        }
        __syncthreads();
    }

    if constexpr (EPI == 1) {
        float rs_[4][4], rq_[4][4];
#pragma unroll
        for (int mi = 0; mi < 4; mi++)
#pragma unroll
            for (int j = 0; j < 4; j++) { rs_[mi][j] = 0.f; rq_[mi][j] = 0.f; }
#pragma unroll
        for (int ni = 0; ni < 4; ni++) {
            int col = n0 + wn + ni * 16 + l16;
            float bl = bias[col];
#pragma unroll
            for (int mi = 0; mi < 4; mi++)
#pragma unroll
                for (int j = 0; j < 4; j++) {
                    int row = m0 + wm + mi * 16 + l4 * 4 + j;
                    float v = acc[mi][ni][j] * scale + bl;
                    float y = 1.5957691216f * (v + 0.044715f * v * v * v);
                    float e = exp2f(-1.4426950409f * y);
                    float gel = v / (1.f + e);
                    unsigned short hb = f2bf(gel);
                    float gv = bf2f(hb);
                    ((unsigned short*)outp)[(size_t)row * H_DIM + col] = hb;
                    rs_[mi][j] += gv;
                    rq_[mi][j] += gv * gv;
                }
        }
#pragma unroll
        for (int mi = 0; mi < 4; mi++)
#pragma unroll
            for (int j = 0; j < 4; j++) {
                float s = rs_[mi][j], q = rq_[mi][j];
#pragma unroll
                for (int off = 1; off <= 8; off <<= 1) { s += __shfl_xor(s, off); q += __shfl_xor(q, off); }
                if (l16 == 0) {
                    int row = m0 + wm + mi * 16 + l4 * 4 + j;
                    atomicAdd(&rsum_g[row], s);
                    atomicAdd(&rsum2_g[row], q);
                }
            }
    } else {
#pragma unroll
        for (int mi = 0; mi < 4; mi++)
#pragma unroll
            for (int j = 0; j < 4; j++) {
                int row = m0 + wm + mi * 16 + l4 * 4 + j;
                float mr = mu2[row], rr = rs2[row];
#pragma unroll
                for (int ni = 0; ni < 4; ni++) {
                    int col = n0 + wn + ni * 16 + l16;
                    float v = scale * (rr * (acc[mi][ni][j] - mr * S1[col]) + S2[col]) + bias[col];
                    ((float*)outp)[(size_t)row * D_DIM + col] = v;
                }
            }
    }
}

extern "C" void kernel_launch(void* const* d_in, const int* in_sizes, int n_in,
                              void* d_out, int out_size, void* d_ws, size_t ws_size,
                              hipStream_t stream) {
    const float* x    = (const float*)d_in[0];
    const float* ln1g = (const float*)d_in[1];
    const float* ln1b = (const float*)d_in[2];
    const float* W1   = (const float*)d_in[3];
    const float* b1   = (const float*)d_in[4];
    const float* ln2g = (const float*)d_in[5];
    const float* ln2b = (const float*)d_in[6];
    const float* W2   = (const float*)d_in[7];
    const float* b2   = (const float*)d_in[8];
    const float* sp   = (const float*)d_in[9];
    const int n1 = in_sizes[3], n2 = in_sizes[7];
    const int M = in_sizes[0] / D_DIM;

    char* ws = (char*)d_ws;
    unsigned* hist1 = (unsigned*)(ws + HIST1_OFF);
    unsigned* hist2 = (unsigned*)(ws + HIST2_OFF);
    unsigned* hist3 = (unsigned*)(ws + HIST3_OFF);
    double*   sums  = (double*)(ws + SUM_OFF);
    double*   thr   = (double*)(ws + THR_OFF);
    unsigned* meta_u = (unsigned*)(ws + META_OFF);
    float*    meta_f = (float*)(ws + META_OFF);
    float* mu2a = (float*)(ws + MU2A_OFF);
    float* ss2a = (float*)(ws + SS2A_OFF);
    float* S1   = (float*)(ws + S1_OFF);
    float* S2   = (float*)(ws + S2_OFF);
    float* mu2  = (float*)(ws + MU2_OFF);
    float* rs2  = (float*)(ws + RS2_OFF);
    unsigned short* wq1 = (unsigned short*)(ws + WQ1_OFF);
    unsigned short* wq2 = (unsigned short*)(ws + WQ2_OFF);
    unsigned short* h1  = (unsigned short*)(ws + H1_OFF);
    unsigned short* xn  = (unsigned short*)d_out;   // scratch until gemm2 overwrites

    hipMemsetAsync(d_ws, 0, ZERO_BYTES, stream);
    hist_abs_kernel<<<dim3(512, 2), 256, 0, stream>>>(W1, n1, W2, n2, hist1, sums);
    scan1_kernel<<<1, 256, 0, stream>>>(hist1, meta_u, sp, n1, n2);
    histN_kernel<2><<<dim3(256, 2), 256, 0, stream>>>(W1, n1, W2, n2, meta_u, hist2);
    scan_mid_kernel<<<1, 256, 0, stream>>>(hist2, meta_u);
    histN_kernel<3><<<dim3(256, 2), 256, 0, stream>>>(W1, n1, W2, n2, meta_u, hist3);
    scan_fin_kernel<<<1, 256, 0, stream>>>(hist3, meta_u, sums, sp, thr, n1, n2);
    quantize_kernel<<<2048, 256, 0, stream>>>(W1, n1, W2, n2, thr, ln2g, wq1, wq2);
    colsum_kernel<<<D_DIM / 4, 256, 0, stream>>>(W2, thr, ln2g, ln2b, S1, S2);
    ln1_apply_kernel<<<M / 4, 256, 0, stream>>>(x, ln1g, ln1b, xn, M);
    gemm_tern_kernel<D_DIM, 24, 1><<<24 * (M / 128), 256, 0, stream>>>(
        xn, wq1, b1, meta_f, 24, h1, mu2a, ss2a, nullptr, nullptr, nullptr, nullptr);
    ln2stats_kernel<<<M / 256, 256, 0, stream>>>(mu2a, ss2a, mu2, rs2, M);
    gemm_tern_kernel<H_DIM, 6, 2><<<6 * (M / 128), 256, 0, stream>>>(
        h1, wq2, b2, meta_f, 25, d_out, nullptr, nullptr, mu2, rs2, S1, S2);
}

// Round 9
// 811.094 us; speedup vs baseline: 1.2179x; 1.2179x over previous
//
#include <hip/hip_runtime.h>
#include <math.h>

using f32x4    = __attribute__((ext_vector_type(4))) float;
using short8   = __attribute__((ext_vector_type(8))) short;
using ushort8  = __attribute__((ext_vector_type(8))) unsigned short;
using ushort4v = __attribute__((ext_vector_type(4))) unsigned short;
using u32x4    = __attribute__((ext_vector_type(4))) unsigned int;

#define D_DIM 768
#define H_DIM 3072

// 3-level radix select on |w| bit pattern: 14 + 9 + 9 bits.
#define L1_BITS 14
#define L1_SIZE 16384

// ---------------- ws layout (bytes) ----------------
static const size_t HIST1_OFF = 0;                        // 131072
static const size_t HIST2_OFF = 131072;                   // 8192
static const size_t HIST3_OFF = 139264;                   // 8192
static const size_t SUM_OFF   = 147456;                   // double[2]
static const size_t THR_OFF   = 147472;                   // double[2]
static const size_t META_OFF  = 147488;                   // u32[32] -> 147616
static const size_t ZERO_BYTES= 147616;
static const size_t S1_OFF    = 147616;                   // f32[768]
static const size_t S2_OFF    = 150688;                   // f32[768]
static const size_t MU2_OFF   = 153760;                   // f32[32768]
static const size_t RS2_OFF   = 284832;                   // f32[32768] -> 415904
static const size_t WQ1_OFF   = 5242880;                  // bf16[3072*768]
static const size_t WQ2_OFF   = 9961472;                  // bf16[768*3072]
static const size_t H1_OFF    = 16777216;                 // bf16[32768*3072]
// d_out reuse: xn (bf16 LN1(x)) at offset 0 (50 MB); row-stat partials at +50331648
// (2 x f32[32768*48] = 12.6 MB). Both dead by the time gemm2 overwrites d_out.
static const size_t PARTS_DOUT_OFF = 50331648;
static const size_t PARTQ_DOUT_OFF = 50331648 + 6291456;

__device__ __forceinline__ unsigned short f2bf(float f) {
    unsigned u = __float_as_uint(f);
    u += 0x7fffu + ((u >> 16) & 1u);
    return (unsigned short)(u >> 16);
}
__device__ __forceinline__ float bf2f(unsigned short s) {
    return __uint_as_float(((unsigned)s) << 16);
}

__device__ __forceinline__ void gload16(const unsigned short* g, unsigned short* l) {
    __builtin_amdgcn_global_load_lds(
        (const __attribute__((address_space(1))) unsigned int*)g,
        (__attribute__((address_space(3))) unsigned int*)l, 16, 0, 0);
}

// ---------------- L1: LDS-privatized 14-bit histogram of |w| + fp64 abs-sum ----------------
__global__ void hist_abs_kernel(const float* __restrict__ W1, int n1,
                                const float* __restrict__ W2, int n2,
                                unsigned* __restrict__ hist, double* __restrict__ sums) {
    __shared__ unsigned lh[L1_SIZE];
    const int t = blockIdx.y;
    const float* W = t ? W2 : W1;
    const int n = t ? n2 : n1;
    unsigned* hg = hist + (size_t)t * L1_SIZE;

    for (int i = threadIdx.x; i < L1_SIZE; i += 256) lh[i] = 0;
    __syncthreads();

    int tid = blockIdx.x * blockDim.x + threadIdx.x;
    int stride = gridDim.x * blockDim.x;
    double local = 0.0;
    int n4 = n >> 2;
    for (int i = tid; i < n4; i += stride) {
        f32x4 w = ((const f32x4*)W)[i];
#pragma unroll
        for (int j = 0; j < 4; j++) {
            float a = fabsf(w[j]);
            local += (double)a;
            atomicAdd(&lh[__float_as_uint(a) >> (32 - L1_BITS)], 1u);
        }
    }
    for (int i = (n4 << 2) + tid; i < n; i += stride) {
        float a = fabsf(W[i]);
        local += (double)a;
        atomicAdd(&lh[__float_as_uint(a) >> (32 - L1_BITS)], 1u);
    }
    __syncthreads();
    for (int i = threadIdx.x; i < L1_SIZE; i += 256) {
        unsigned c = lh[i];
        if (c) atomicAdd(&hg[i], c);
    }
#pragma unroll
    for (int off = 32; off >= 1; off >>= 1) local += __shfl_down(local, off);
    if ((threadIdx.x & 63) == 0) atomicAdd(&sums[t], local);
}

// ---------------- L1 scan ----------------
__global__ void scan1_kernel(const unsigned* __restrict__ hist, unsigned* __restrict__ meta_u,
                             const float* __restrict__ sparsity, int n1, int n2) {
    __shared__ unsigned partial[256];
    __shared__ unsigned basearr[256];
    for (int t = 0; t < 2; t++) {
        const unsigned* h = hist + (size_t)t * L1_SIZE;
        int n = t ? n2 : n1;
        double p = (double)(*sparsity) * (double)(n - 1);
        unsigned kA = (unsigned)floor(p);
        unsigned kB = kA + 1; if (kB > (unsigned)(n - 1)) kB = (unsigned)(n - 1);
        int b0 = threadIdx.x * 64;
        unsigned s_local = 0;
#pragma unroll
        for (int b = 0; b < 64; b += 4) {
            u32x4 v = *(const u32x4*)&h[b0 + b];
            s_local += v[0] + v[1] + v[2] + v[3];
        }
        partial[threadIdx.x] = s_local;
        __syncthreads();
        if (threadIdx.x == 0) {
            unsigned run = 0;
            for (int i = 0; i < 256; i++) { unsigned tmp = partial[i]; basearr[i] = run; run += tmp; }
        }
        __syncthreads();
        unsigned cumbase = basearr[threadIdx.x];
        for (int s = 0; s < 2; s++) {
            unsigned rank = s ? kB : kA;
            if (rank >= cumbase && rank < cumbase + s_local) {
                unsigned cum = cumbase;
                for (int b = 0; b < 64; b++) {
                    unsigned c = h[b0 + b];
                    if (rank < cum + c) { meta_u[s * 4 + t] = (unsigned)(b0 + b); meta_u[s * 4 + 2 + t] = rank - cum; break; }
                    cum += c;
                }
            }
        }
        __syncthreads();
    }
}

// ---------------- L2/L3 histograms (512 buckets, LDS-privatized) ----------
template<int LVL>
__global__ void histN_kernel(const float* __restrict__ W1, int n1,
                             const float* __restrict__ W2, int n2,
                             const unsigned* __restrict__ meta_u, unsigned* __restrict__ histo) {
    __shared__ unsigned hA[512], hB[512];
    const int t = blockIdx.y;
    const float* W = t ? W2 : W1;
    const int n = t ? n2 : n1;
    for (int i = threadIdx.x; i < 512; i += 256) { hA[i] = 0; hB[i] = 0; }
    __syncthreads();
    const int inbase = (LVL == 2) ? 0 : 16;
    unsigned pa = meta_u[inbase + 0 + t], pb = meta_u[inbase + 4 + t];
    int tid = blockIdx.x * blockDim.x + threadIdx.x;
    int stride = gridDim.x * blockDim.x;
    int n4 = n >> 2;
    for (int i = tid; i < n4; i += stride) {
        f32x4 w = ((const f32x4*)W)[i];
#pragma unroll
        for (int j = 0; j < 4; j++) {
            unsigned u = __float_as_uint(fabsf(w[j]));
            unsigned pf  = (LVL == 2) ? (u >> 18) : (u >> 9);
            unsigned idx = (LVL == 2) ? ((u >> 9) & 0x1FFu) : (u & 0x1FFu);
            if (pf == pa) atomicAdd(&hA[idx], 1u);
            if (pf == pb) atomicAdd(&hB[idx], 1u);
        }
    }
    for (int i = (n4 << 2) + tid; i < n; i += stride) {
        unsigned u = __float_as_uint(fabsf(W[i]));
        unsigned pf  = (LVL == 2) ? (u >> 18) : (u >> 9);
        unsigned idx = (LVL == 2) ? ((u >> 9) & 0x1FFu) : (u & 0x1FFu);
        if (pf == pa) atomicAdd(&hA[idx], 1u);
        if (pf == pb) atomicAdd(&hB[idx], 1u);
    }
    __syncthreads();
    for (int i = threadIdx.x; i < 512; i += 256) {
        unsigned a = hA[i]; if (a) atomicAdd(&histo[(size_t)(t * 2 + 0) * 512 + i], a);
        unsigned b = hB[i]; if (b) atomicAdd(&histo[(size_t)(t * 2 + 1) * 512 + i], b);
    }
}

// ---------------- L2 scan ------------
__global__ void scan_mid_kernel(const unsigned* __restrict__ histo, unsigned* __restrict__ meta_u) {
    int wave = threadIdx.x >> 6, lane = threadIdx.x & 63;
    int s = wave >> 1, t = wave & 1;
    const unsigned* h = histo + (size_t)(t * 2 + s) * 512;
    unsigned rank = meta_u[s * 4 + 2 + t];
    unsigned pfx  = meta_u[s * 4 + t];
    u32x4 ca = *(const u32x4*)&h[lane * 8];
    u32x4 cb = *(const u32x4*)&h[lane * 8 + 4];
    unsigned cc[8] = {ca[0], ca[1], ca[2], ca[3], cb[0], cb[1], cb[2], cb[3]};
    unsigned csum = cc[0] + cc[1] + cc[2] + cc[3] + cc[4] + cc[5] + cc[6] + cc[7];
    unsigned inc = csum;
#pragma unroll
    for (int off = 1; off < 64; off <<= 1) {
        unsigned v = __shfl_up(inc, off, 64);
        if (lane >= off) inc += v;
    }
    unsigned pre = inc - csum;
    if (rank >= pre && rank < pre + csum) {
        unsigned cum = pre, rem = 0, bucket = 0; bool found = false;
#pragma unroll
        for (int j = 0; j < 8; j++) {
            if (!found) {
                if (rank < cum + cc[j]) { bucket = lane * 8 + j; rem = rank - cum; found = true; }
                else cum += cc[j];
            }
        }
        meta_u[16 + s * 4 + t] = (pfx << 9) | bucket;
        meta_u[16 + s * 4 + 2 + t] = rem;
    }
}

// ---------------- L3 scan -> fp64 threshold + scale ----------------------
__global__ void scan_fin_kernel(const unsigned* __restrict__ histo, unsigned* __restrict__ meta_u,
                                const double* __restrict__ sums, const float* __restrict__ sparsity,
                                double* __restrict__ thr, int n1, int n2) {
    __shared__ unsigned vbs[4];
    int wave = threadIdx.x >> 6, lane = threadIdx.x & 63;
    int s = wave >> 1, t = wave & 1;
    const unsigned* h = histo + (size_t)(t * 2 + s) * 512;
    unsigned rank = meta_u[16 + s * 4 + 2 + t];
    unsigned pfx  = meta_u[16 + s * 4 + t];
    u32x4 ca = *(const u32x4*)&h[lane * 8];
    u32x4 cb = *(const u32x4*)&h[lane * 8 + 4];
    unsigned cc[8] = {ca[0], ca[1], ca[2], ca[3], cb[0], cb[1], cb[2], cb[3]};
    unsigned csum = cc[0] + cc[1] + cc[2] + cc[3] + cc[4] + cc[5] + cc[6] + cc[7];
    unsigned inc = csum;
#pragma unroll
    for (int off = 1; off < 64; off <<= 1) {
        unsigned v = __shfl_up(inc, off, 64);
        if (lane >= off) inc += v;
    }
    unsigned pre = inc - csum;
    if (rank >= pre && rank < pre + csum) {
        unsigned cum = pre, bucket = 0; bool found = false;
#pragma unroll
        for (int j = 0; j < 8; j++) {
            if (!found) {
                if (rank < cum + cc[j]) { bucket = lane * 8 + j; found = true; }
                else cum += cc[j];
            }
        }
        vbs[t * 2 + s] = (pfx << 9) | bucket;
    }
    __syncthreads();
    if (threadIdx.x < 2) {
        int tt = threadIdx.x;
        int n = tt ? n2 : n1;
        double a = (double)__uint_as_float(vbs[tt * 2 + 0]);
        double b = (double)__uint_as_float(vbs[tt * 2 + 1]);
        double p = (double)(*sparsity) * (double)(n - 1);
        double tfr = p - floor(p);
        double th = (tfr >= 0.5) ? (b - (b - a) * (1.0 - tfr)) : (a + (b - a) * tfr);
        thr[tt] = th;
        ((float*)meta_u)[24 + tt] = (float)(sums[tt] / (double)n);
    }
}

// ---------------- ternary quantize: wq1 = sign, wq2 = sign*bf16(g2[k]) ----------------
__global__ void quantize_kernel(const float* __restrict__ W1, int n1,
                                const float* __restrict__ W2, int n2,
                                const double* __restrict__ thr, const float* __restrict__ g2,
                                unsigned short* __restrict__ wq1, unsigned short* __restrict__ wq2) {
    int tid = blockIdx.x * blockDim.x + threadIdx.x;
    int stride = gridDim.x * blockDim.x;
    for (int t = 0; t < 2; t++) {
        const float* W = t ? W2 : W1;
        unsigned short* O = t ? wq2 : wq1;
        int n = t ? n2 : n1;
        double th = thr[t];
        int n4 = n >> 2;
        for (int i = tid; i < n4; i += stride) {
            f32x4 w = ((const f32x4*)W)[i];
            ushort4v q;
            if (t == 0) {
#pragma unroll
                for (int j = 0; j < 4; j++) {
                    unsigned short v = 0;
                    if ((double)fabsf(w[j]) > th) v = (w[j] > 0.f) ? 0x3F80u : 0xBF80u;
                    q[j] = v;
                }
            } else {
                int k4 = (i % (H_DIM / 4)) * 4;
                f32x4 g = *(const f32x4*)&g2[k4];
#pragma unroll
                for (int j = 0; j < 4; j++) {
                    unsigned short v = 0;
                    if ((double)fabsf(w[j]) > th) {
                        unsigned short gb = f2bf(g[j]);
                        v = (w[j] > 0.f) ? gb : (unsigned short)(gb ^ 0x8000u);
                    }
                    q[j] = v;
                }
            }
            ((ushort4v*)O)[i] = q;
        }
    }
}

// ---------------- column correction sums for gemm2: S1[c]=Σ bf16(g)·q, S2[c]=Σ bβ·q ----------
__global__ void colsum_kernel(const float* __restrict__ W2, const double* __restrict__ thr,
                              const float* __restrict__ g2, const float* __restrict__ bln2,
                              float* __restrict__ S1, float* __restrict__ S2) {
    int wave = threadIdx.x >> 6, lane = threadIdx.x & 63;
    int c = blockIdx.x * 4 + wave;
    const float* wr = W2 + (size_t)c * H_DIM;
    double th = thr[1];
    float s1 = 0.f, s2 = 0.f;
    for (int k = lane * 4; k < H_DIM; k += 256) {
        f32x4 w = *(const f32x4*)&wr[k];
        f32x4 g = *(const f32x4*)&g2[k];
        f32x4 b = *(const f32x4*)&bln2[k];
#pragma unroll
        for (int j = 0; j < 4; j++) {
            if ((double)fabsf(w[j]) > th) {
                float sg = (w[j] > 0.f) ? 1.f : -1.f;
                s1 += sg * bf2f(f2bf(g[j]));
                s2 += sg * b[j];
            }
        }
    }
#pragma unroll
    for (int off = 32; off >= 1; off >>= 1) { s1 += __shfl_xor(s1, off); s2 += __shfl_xor(s2, off); }
    if (lane == 0) { S1[c] = s1; S2[c] = s2; }
}

// ---------------- LN1: stats + apply, write xn bf16 ----------------
__global__ void ln1_apply_kernel(const float* __restrict__ x, const float* __restrict__ g,
                                 const float* __restrict__ b, unsigned short* __restrict__ xn, int M) {
    int wave = threadIdx.x >> 6, lane = threadIdx.x & 63;
    int row = blockIdx.x * 4 + wave;
    if (row >= M) return;
    const float* xr = x + (size_t)row * D_DIM;
    f32x4 xv[3];
    float s = 0.f, s2 = 0.f;
#pragma unroll
    for (int i = 0; i < 3; i++) {
        xv[i] = *(const f32x4*)&xr[lane * 4 + i * 256];
#pragma unroll
        for (int j = 0; j < 4; j++) { s += xv[i][j]; s2 += xv[i][j] * xv[i][j]; }
    }
#pragma unroll
    for (int off = 32; off >= 1; off >>= 1) { s += __shfl_xor(s, off); s2 += __shfl_xor(s2, off); }
    float m = s / (float)D_DIM;
    float var = s2 / (float)D_DIM - m * m;
    float rs = 1.f / sqrtf(var + 1e-5f);
    unsigned short* xo = xn + (size_t)row * D_DIM;
#pragma unroll
    for (int i = 0; i < 3; i++) {
        int k = lane * 4 + i * 256;
        f32x4 gg = *(const f32x4*)&g[k];
        f32x4 bb = *(const f32x4*)&b[k];
        ushort4v o;
#pragma unroll
        for (int j = 0; j < 4; j++) o[j] = f2bf((xv[i][j] - m) * rs * gg[j] + bb[j]);
        *(ushort4v*)&xo[k] = o;
    }
}

// ---------------- finalize LN2 stats: reduce 48 partial slots per row ----------------
__global__ void ln2stats_kernel(const float* __restrict__ parts, const float* __restrict__ partq,
                                float* __restrict__ mu, float* __restrict__ rs, int M) {
    int i = blockIdx.x * 256 + threadIdx.x;
    if (i >= M) return;
    const float* ps = parts + (size_t)i * 48;
    const float* pq = partq + (size_t)i * 48;
    float s = 0.f, q = 0.f;
#pragma unroll
    for (int j = 0; j < 48; j += 4) {
        f32x4 a = *(const f32x4*)&ps[j];
        f32x4 b = *(const f32x4*)&pq[j];
        s += a[0] + a[1] + a[2] + a[3];
        q += b[0] + b[1] + b[2] + b[3];
    }
    float m = s / (float)H_DIM;
    float var = q / (float)H_DIM - m * m;
    mu[i] = m;
    rs[i] = 1.f / sqrtf(var + 1e-5f);
}

// ---------------- bf16 GEMM: C = A @ Bq^T, 128x128 tile, BK=64, gload_lds + XOR swizzle ----
// EPI 1 (gemm1): h1 = bf16(gelu(acc*scale+bias)); per-block row Σ/Σ² partials (no atomics).
// EPI 2 (gemm2): out = scale*(rs[r]*(acc - mu[r]*S1[c]) + S2[c]) + bias[c], fp32.
template<int KD, int EPI>
__launch_bounds__(256)
__global__ void gemm_tern_kernel(const unsigned short* __restrict__ A,
                                 const unsigned short* __restrict__ Bq,
                                 const float* __restrict__ bias,
                                 const float* __restrict__ meta_f, int sidx,
                                 void* __restrict__ outp,
                                 float* __restrict__ parts, float* __restrict__ partq,
                                 const float* __restrict__ mu2, const float* __restrict__ rs2,
                                 const float* __restrict__ S1, const float* __restrict__ S2) {
    __shared__ unsigned short As[128 * 64];
    __shared__ unsigned short Bs[128 * 64];
    const int m0 = blockIdx.y * 128, n0 = blockIdx.x * 128;
    const float scale = meta_f[sidx];
    const int tt = threadIdx.x, lane = tt & 63, wave = tt >> 6;
    const int wm = (wave & 1) * 64, wn = (wave >> 1) * 64;
    const int l16 = lane & 15, l4 = lane >> 4;
    const int srow = tt >> 3, schunk = tt & 7;

    f32x4 acc[4][4];
#pragma unroll
    for (int mi = 0; mi < 4; mi++)
#pragma unroll
        for (int ni = 0; ni < 4; ni++) acc[mi][ni] = (f32x4){0.f, 0.f, 0.f, 0.f};

    for (int k0 = 0; k0 < KD; k0 += 64) {
#pragma unroll
        for (int r = 0; r < 4; r++) {
            int row = r * 32 + srow;
            int sc = (schunk ^ (row & 7)) << 3;
            gload16(&A[(size_t)(m0 + row) * KD + k0 + sc], &As[(size_t)tt * 8 + r * 2048]);
        }
#pragma unroll
        for (int r = 0; r < 4; r++) {
            int row = r * 32 + srow;
            int sc = (schunk ^ (row & 7)) << 3;
            gload16(&Bq[(size_t)(n0 + row) * KD + k0 + sc], &Bs[(size_t)tt * 8 + r * 2048]);
        }
        __syncthreads();
#pragma unroll
        for (int ks = 0; ks < 2; ks++) {
            short8 af[4], bf_[4];
#pragma unroll
            for (int i = 0; i < 4; i++) {
                int ar = wm + i * 16 + l16;
                af[i] = *(const short8*)&As[ar * 64 + (((ks * 4 + l4) ^ (ar & 7)) << 3)];
                int br = wn + i * 16 + l16;
                bf_[i] = *(const short8*)&Bs[br * 64 + (((ks * 4 + l4) ^ (br & 7)) << 3)];
            }
#pragma unroll
            for (int mi = 0; mi < 4; mi++)
#pragma unroll
                for (int ni = 0; ni < 4; ni++)
                    acc[mi][ni] = __builtin_amdgcn_mfma_f32_16x16x32_bf16(af[mi], bf_[ni], acc[mi][ni], 0, 0, 0);
        }
        __syncthreads();
    }

    if constexpr (EPI == 1) {
        float rs_[4][4], rq_[4][4];
#pragma unroll
        for (int mi = 0; mi < 4; mi++)
#pragma unroll
            for (int j = 0; j < 4; j++) { rs_[mi][j] = 0.f; rq_[mi][j] = 0.f; }
#pragma unroll
        for (int ni = 0; ni < 4; ni++) {
            int col = n0 + wn + ni * 16 + l16;
            float bl = bias[col];
#pragma unroll
            for (int mi = 0; mi < 4; mi++)
#pragma unroll
                for (int j = 0; j < 4; j++) {
                    int row = m0 + wm + mi * 16 + l4 * 4 + j;
                    float v = acc[mi][ni][j] * scale + bl;
                    float y = 1.5957691216f * (v + 0.044715f * v * v * v);
                    float e = exp2f(-1.4426950409f * y);
                    float gel = v / (1.f + e);
                    unsigned short hb = f2bf(gel);
                    float gv = bf2f(hb);
                    ((unsigned short*)outp)[(size_t)row * H_DIM + col] = hb;
                    rs_[mi][j] += gv;
                    rq_[mi][j] += gv * gv;
                }
        }
        // reduce over the 16 l16 lanes; one writer per (mi,j,l4); slot = nb*2 + wn-half
        const int slot = blockIdx.x * 2 + (wave >> 1);
#pragma unroll
        for (int mi = 0; mi < 4; mi++)
#pragma unroll
            for (int j = 0; j < 4; j++) {
                float s = rs_[mi][j], q = rq_[mi][j];
#pragma unroll
                for (int off = 1; off <= 8; off <<= 1) { s += __shfl_xor(s, off); q += __shfl_xor(q, off); }
                if (l16 == 0) {
                    int row = m0 + wm + mi * 16 + l4 * 4 + j;
                    parts[(size_t)row * 48 + slot] = s;
                    partq[(size_t)row * 48 + slot] = q;
                }
            }
    } else {
#pragma unroll
        for (int mi = 0; mi < 4; mi++)
#pragma unroll
            for (int j = 0; j < 4; j++) {
                int row = m0 + wm + mi * 16 + l4 * 4 + j;
                float mr = mu2[row], rr = rs2[row];
#pragma unroll
                for (int ni = 0; ni < 4; ni++) {
                    int col = n0 + wn + ni * 16 + l16;
                    float v = scale * (rr * (acc[mi][ni][j] - mr * S1[col]) + S2[col]) + bias[col];
                    ((float*)outp)[(size_t)row * D_DIM + col] = v;
                }
            }
    }
}

extern "C" void kernel_launch(void* const* d_in, const int* in_sizes, int n_in,
                              void* d_out, int out_size, void* d_ws, size_t ws_size,
                              hipStream_t stream) {
    const float* x    = (const float*)d_in[0];
    const float* ln1g = (const float*)d_in[1];
    const float* ln1b = (const float*)d_in[2];
    const float* W1   = (const float*)d_in[3];
    const float* b1   = (const float*)d_in[4];
    const float* ln2g = (const float*)d_in[5];
    const float* ln2b = (const float*)d_in[6];
    const float* W2   = (const float*)d_in[7];
    const float* b2   = (const float*)d_in[8];
    const float* sp   = (const float*)d_in[9];
    const int n1 = in_sizes[3], n2 = in_sizes[7];
    const int M = in_sizes[0] / D_DIM;

    char* ws = (char*)d_ws;
    unsigned* hist1 = (unsigned*)(ws + HIST1_OFF);
    unsigned* hist2 = (unsigned*)(ws + HIST2_OFF);
    unsigned* hist3 = (unsigned*)(ws + HIST3_OFF);
    double*   sums  = (double*)(ws + SUM_OFF);
    double*   thr   = (double*)(ws + THR_OFF);
    unsigned* meta_u = (unsigned*)(ws + META_OFF);
    float*    meta_f = (float*)(ws + META_OFF);
    float* S1   = (float*)(ws + S1_OFF);
    float* S2   = (float*)(ws + S2_OFF);
    float* mu2  = (float*)(ws + MU2_OFF);
    float* rs2  = (float*)(ws + RS2_OFF);
    unsigned short* wq1 = (unsigned short*)(ws + WQ1_OFF);
    unsigned short* wq2 = (unsigned short*)(ws + WQ2_OFF);
    unsigned short* h1  = (unsigned short*)(ws + H1_OFF);
    unsigned short* xn  = (unsigned short*)d_out;                      // scratch until gemm2
    float* parts = (float*)((char*)d_out + PARTS_DOUT_OFF);            // scratch until gemm2
    float* partq = (float*)((char*)d_out + PARTQ_DOUT_OFF);

    hipMemsetAsync(d_ws, 0, ZERO_BYTES, stream);
    hist_abs_kernel<<<dim3(512, 2), 256, 0, stream>>>(W1, n1, W2, n2, hist1, sums);
    scan1_kernel<<<1, 256, 0, stream>>>(hist1, meta_u, sp, n1, n2);
    histN_kernel<2><<<dim3(256, 2), 256, 0, stream>>>(W1, n1, W2, n2, meta_u, hist2);
    scan_mid_kernel<<<1, 256, 0, stream>>>(hist2, meta_u);
    histN_kernel<3><<<dim3(256, 2), 256, 0, stream>>>(W1, n1, W2, n2, meta_u, hist3);
    scan_fin_kernel<<<1, 256, 0, stream>>>(hist3, meta_u, sums, sp, thr, n1, n2);
    quantize_kernel<<<2048, 256, 0, stream>>>(W1, n1, W2, n2, thr, ln2g, wq1, wq2);
    colsum_kernel<<<D_DIM / 4, 256, 0, stream>>>(W2, thr, ln2g, ln2b, S1, S2);
    ln1_apply_kernel<<<M / 4, 256, 0, stream>>>(x, ln1g, ln1b, xn, M);
    gemm_tern_kernel<D_DIM, 1><<<dim3(H_DIM / 128, M / 128), 256, 0, stream>>>(
        xn, wq1, b1, meta_f, 24, h1, parts, partq, nullptr, nullptr, nullptr, nullptr);
    ln2stats_kernel<<<M / 256, 256, 0, stream>>>(parts, partq, mu2, rs2, M);
    gemm_tern_kernel<H_DIM, 2><<<dim3(D_DIM / 128, M / 128), 256, 0, stream>>>(
        h1, wq2, b2, meta_f, 25, d_out, nullptr, nullptr, mu2, rs2, S1, S2);
}